// Round 17
// baseline (391.893 us; speedup 1.0000x reference)
//
#include <hip/hip_runtime.h>

#define BS_TOTAL 32768   // B*S
#define DB 768
#define KV 832           // padded K: 768 enc + 50 ent + 14 zero
#define KREAL 818
#define TT 68
#define SEQ 512

typedef float v2f __attribute__((ext_vector_type(2)));
typedef float f32x4 __attribute__((ext_vector_type(4)));
typedef _Float16 f16x8 __attribute__((ext_vector_type(8)));
typedef _Float16 f16x4 __attribute__((ext_vector_type(4)));
typedef unsigned int uint;
typedef unsigned short ushort;

union U4 { uint4 u; f16x8 h; };

__device__ __forceinline__ _Float16 us2h(ushort x){ union{ushort u;_Float16 h;}c; c.u=x; return c.h; }
__device__ __forceinline__ ushort h2us(_Float16 x){ union{ushort u;_Float16 h;}c; c.h=x; return c.u; }
__device__ __forceinline__ uint packx(float xs){
    _Float16 h=(_Float16)xs; _Float16 l=(_Float16)(xs-(float)h);
    return (uint)h2us(h) | ((uint)h2us(l)<<16);
}

// ---------------- K0pre: pre-split A = concat(enc, ent)*32 -> f16 hi/lo planes [32768][832].
// Bit-identical math to the proven in-fc1 split (incl. ent gather order); computed once, not 6x.
__global__ __launch_bounds__(256) void presplit_kernel(
    const float* __restrict__ enc, const int* __restrict__ ex,
    const float* __restrict__ table,
    _Float16* __restrict__ Ahi, _Float16* __restrict__ Alo)
{
    int g = blockIdx.x * 256 + threadIdx.x;      // 32768*104 chunks of 8
    int row = g / 104;
    int c8 = (g - row * 104) * 8;                // k offset, multiple of 8
    float v[8];
    if (c8 < DB) {
        float4 f0 = *reinterpret_cast<const float4*>(enc + (size_t)row * DB + c8);
        float4 f1 = *reinterpret_cast<const float4*>(enc + (size_t)row * DB + c8 + 4);
        v[0]=f0.x; v[1]=f0.y; v[2]=f0.z; v[3]=f0.w;
        v[4]=f1.x; v[5]=f1.y; v[6]=f1.z; v[7]=f1.w;
    } else {
        const int* exr = ex + (size_t)row * 3;
        int i0 = exr[0] * 50, i1 = exr[1] * 50, i2 = exr[2] * 50;
#pragma unroll
        for (int j = 0; j < 8; ++j) {
            int e = c8 + j - DB;
            v[j] = (e < 50) ? (table[i0 + e] + table[i1 + e] + table[i2 + e]) : 0.f;
        }
    }
    f16x8 hi, lo;
#pragma unroll
    for (int j = 0; j < 8; ++j) {
        float s = v[j] * 32.f;
        _Float16 h = (_Float16)s;
        hi[j] = h; lo[j] = (_Float16)(s - (float)h);
    }
    *reinterpret_cast<f16x8*>(Ahi + (size_t)row * KV + c8) = hi;
    *reinterpret_cast<f16x8*>(Alo + (size_t)row * KV + c8) = lo;
}

// ---------------- K0a: pack fc1 W into MFMA-fragment-linear f16 hi/lo slabs (x1024).
// (R16-proven verbatim)
__global__ __launch_bounds__(64) void packwf_kernel(
    const float* __restrict__ W, _Float16* __restrict__ Wf)
{
    const int bid = blockIdx.x;          // 6*13*16 = 1248
    const int l = threadIdx.x;
    const int bn = bid / 208;
    const int rem = bid % 208;
    const int kt = rem >> 4;
    const int sub = rem & 15;
    const int ks = sub >> 3;
    const int nfg = sub & 7;
    const int row = bn * 128 + nfg * 16 + (l & 15);
    const int kb = kt * 64 + ks * 32 + ((l >> 4) << 3);
    f16x8 hi, lo;
#pragma unroll
    for (int q = 0; q < 8; ++q) {
        int k = kb + q;
        float v = (k < KREAL) ? W[(size_t)row * KREAL + k] * 1024.f : 0.f;
        _Float16 h = (_Float16)v;
        hi[q] = h; lo[q] = (_Float16)(v - (float)h);
    }
    const size_t fb = ((((size_t)bn * 13 + kt) * 2 + ks) * 8 + nfg) * 2;
    *reinterpret_cast<f16x8*>(Wf + (fb + 0) * 512 + l * 8) = hi;
    *reinterpret_cast<f16x8*>(Wf + (fb + 1) * 512 + l * 8) = lo;
}

// ---------------- K0b: split trig W rows -> T0/T1 row-major [80][768], x1024 (proven verbatim)
__global__ __launch_bounds__(256) void splitw_trig(
    const float* __restrict__ Wt, _Float16* __restrict__ T0, _Float16* __restrict__ T1)
{
    int r2 = blockIdx.x;               // 0..79
    int t = threadIdx.x;
#pragma unroll
    for (int j = 0; j < 3; ++j) {
        int k = t * 3 + j;
        if (k < DB) {
            float v = (r2 < TT) ? Wt[(size_t)r2 * DB + k] * 1024.f : 0.f;
            _Float16 h = (_Float16)v;
            T0[(size_t)r2 * DB + k] = h;
            T1[(size_t)r2 * DB + k] = (_Float16)(v - (float)h);
        }
    }
}

// ---------------- K1: fc1 via fp32-emu fp16 MFMA. A staged from pre-split global planes
// (pure uint4 copies, zero staging VALU; same LDS byte-map as proven kernel). W fragments
// global->registers (R16-proven). XCD-chunked bijective grid (1536 = 8*192, bn fastest).
// Epilogue = proven LDS-staged coalesced packed stores.
__global__ __launch_bounds__(256, 2) void fc1_mfma(
    const _Float16* __restrict__ Ahi, const _Float16* __restrict__ Alo,
    const _Float16* __restrict__ Wf,
    const float* __restrict__ bias, uint* __restrict__ xout)
{
    __shared__ char lds[32768];
    char* sA0 = lds;
    char* sA1 = lds + 16384;
    const int t = threadIdx.x;
    const int l = t & 63;
    const int w = t >> 6;
    const int wr = w >> 1, wc = w & 1;
    const int lr = l & 15, hi2 = l >> 4;
    const int bid = blockIdx.x;
    const int wgid = (bid & 7) * 192 + (bid >> 3);   // XCD-chunked, bijective
    const int bm0 = (wgid / 6) * 128;
    const int by = wgid % 6;
    const int bn0 = by * 128;

    f32x4 acc[4][4];
#pragma unroll
    for (int i = 0; i < 4; ++i)
#pragma unroll
        for (int j = 0; j < 4; ++j) acc[i][j] = (f32x4){0.f, 0.f, 0.f, 0.f};

    uint4 pa[8];      // A prefetch: [0..3] hi plane, [4..7] lo plane
    uint4 bf[8];      // B fragments for one ks

    auto loadA = [&](int kt) {
        const int k0 = kt * 64;
#pragma unroll
        for (int c = 0; c < 4; ++c) {
            int idx = t + c * 256;
            int r = idx >> 3;
            int h8 = (idx & 7) << 3;
            size_t goff = (size_t)(bm0 + r) * KV + k0 + h8;
            pa[c]     = *reinterpret_cast<const uint4*>(Ahi + goff);
            pa[c + 4] = *reinterpret_cast<const uint4*>(Alo + goff);
        }
    };
    auto loadBf = [&](int kt, int ks) {
        const size_t fb = ((((size_t)by * 13 + kt) * 2 + ks) * 8 + wc * 4) * 2;
        const _Float16* base = Wf + fb * 512 + l * 8;
#pragma unroll
        for (int q = 0; q < 8; ++q)
            bf[q] = *reinterpret_cast<const uint4*>(base + (size_t)q * 512);
    };

    loadA(0); loadBf(0, 0);

    for (int kt = 0; kt < 13; ++kt) {
        __syncthreads();
        // ---- stage A tile: pure b128 copies, same swizzled byte-map as proven kernel
#pragma unroll
        for (int c = 0; c < 4; ++c) {
            int idx = t + c * 256;
            int r = idx >> 3;
            int b16 = (idx & 7) << 4;
            int off = (r << 7) + (b16 ^ ((r & 7) << 4));
            *reinterpret_cast<uint4*>(sA0 + off) = pa[c];
            *reinterpret_cast<uint4*>(sA1 + off) = pa[c + 4];
        }
        __syncthreads();
        if (kt < 12) loadA(kt + 1);       // overlap with MFMA
        // ---- compute: 2 k-steps; B frags from registers, A frags from LDS (proven verbatim)
#pragma unroll
        for (int ks = 0; ks < 2; ++ks) {
            const int kb = ks * 64 + (hi2 << 4);
            f16x8 a0f[4], a1f[4], b0f[4], b1f[4];
#pragma unroll
            for (int mf = 0; mf < 4; ++mf) {
                int r = wr * 64 + mf * 16 + lr;
                int off = (r << 7) + (kb ^ ((r & 7) << 4));
                a0f[mf] = *reinterpret_cast<const f16x8*>(sA0 + off);
                a1f[mf] = *reinterpret_cast<const f16x8*>(sA1 + off);
            }
#pragma unroll
            for (int nf = 0; nf < 4; ++nf) {
                U4 u0, u1;
                u0.u = bf[nf * 2 + 0];
                u1.u = bf[nf * 2 + 1];
                b0f[nf] = u0.h;
                b1f[nf] = u1.h;
            }
            if (ks == 0) loadBf(kt, 1);
            else if (kt < 12) loadBf(kt + 1, 0);
#pragma unroll
            for (int mf = 0; mf < 4; ++mf)
#pragma unroll
                for (int nf = 0; nf < 4; ++nf) {
                    acc[mf][nf] = __builtin_amdgcn_mfma_f32_16x16x32_f16(a0f[mf], b0f[nf], acc[mf][nf], 0, 0, 0);
                    acc[mf][nf] = __builtin_amdgcn_mfma_f32_16x16x32_f16(a1f[mf], b0f[nf], acc[mf][nf], 0, 0, 0);
                    acc[mf][nf] = __builtin_amdgcn_mfma_f32_16x16x32_f16(a0f[mf], b1f[nf], acc[mf][nf], 0, 0, 0);
                }
        }
    }

    // ---- epilogue (proven): unscale 2^-15, bias, relu, pack(x*256), LDS-staged stores
    const float inv0 = 1.0f / 32768.f;
    uint* sE = reinterpret_cast<uint*>(lds);   // [32][132]
    float bv[4];
#pragma unroll
    for (int nf = 0; nf < 4; ++nf) bv[nf] = bias[bn0 + wc * 64 + nf * 16 + lr];

#pragma unroll
    for (int p = 0; p < 4; ++p) {
        __syncthreads();
        if (wr == (p >> 1)) {
#pragma unroll
            for (int mi = 0; mi < 2; ++mi) {
                int mf = (p & 1) * 2 + mi;
                int rowl = mf * 16 + hi2 * 4 - (p & 1) * 32;
#pragma unroll
                for (int nf = 0; nf < 4; ++nf) {
                    int col = wc * 64 + nf * 16 + lr;
#pragma unroll
                    for (int j = 0; j < 4; ++j) {
                        float x = fmaxf(acc[mf][nf][j] * inv0 + bv[nf], 0.f);
                        sE[(rowl + j) * 132 + col] = packx(x * 256.f);
                    }
                }
            }
        }
        __syncthreads();
        int rrow = t >> 3;
        int c0 = (t & 7) << 4;
        uint* gp = xout + (size_t)(bm0 + p * 32 + rrow) * DB + bn0 + c0;
        const uint* sp = sE + rrow * 132 + c0;
#pragma unroll
        for (int q = 0; q < 4; ++q)
            *reinterpret_cast<uint4*>(gp + q * 4) = *reinterpret_cast<const uint4*>(sp + q * 4);
    }
}

// ---------------- K2: trig GEMM via emu-MFMA. 64 gathered rows/block, N=80 (5 nf), BK=64.
// (R8/R15/R16-proven verbatim)
__global__ __launch_bounds__(256, 4) void trig_mfma(
    const uint* __restrict__ xfc, const int* __restrict__ head_idx,
    const _Float16* __restrict__ T0, const _Float16* __restrict__ T1,
    const float* __restrict__ bt, float* __restrict__ logits, float* __restrict__ hat)
{
    __shared__ char sA[16384];   // [64][256B]: hi 0-127 | lo 128-255
    __shared__ char sW[20480];   // [80][256B]
    __shared__ int srow[64];
    const int t = threadIdx.x;
    const int l = t & 63;
    const int w = t >> 6;
    const int lr = l & 15, hi2 = l >> 4;
    const int s0 = blockIdx.x * 64;
    if (t < 64) srow[t] = (((s0 + t) >> 9) << 9) + head_idx[s0 + t];
    __syncthreads();

    f32x4 acc[5];
#pragma unroll
    for (int n = 0; n < 5; ++n) acc[n] = (f32x4){0.f, 0.f, 0.f, 0.f};

    uint4 pa[4];
    uint4 pw[5];

    auto loadA = [&](int k0) {
        int r = t >> 2, c16 = (t & 3) << 4;
        const uint* src = xfc + (size_t)srow[r] * DB + k0 + c16;
#pragma unroll
        for (int q = 0; q < 4; ++q) pa[q] = *reinterpret_cast<const uint4*>(src + q * 4);
    };
    auto loadW = [&](int k0) {
#pragma unroll
        for (int i = 0; i < 5; ++i) {
            int cid = t + i * 256;
            int row = cid >> 4;
            int sl = cid & 15;
            const _Float16* src = ((sl >> 3) ? T1 : T0) + (size_t)row * DB + k0 + (sl & 7) * 8;
            pw[i] = *reinterpret_cast<const uint4*>(src);
        }
    };

    loadA(0); loadW(0);

    for (int kt = 0; kt < 12; ++kt) {
        __syncthreads();
        // A: unpack 16 packed uints -> hi/lo f16 planes
        {
            int r = t >> 2, c16 = (t & 3) << 4;
            int sw = (r & 7) << 4;
            uint uu[16];
#pragma unroll
            for (int q = 0; q < 4; ++q) *reinterpret_cast<uint4*>(uu + q * 4) = pa[q];
            U4 h0, h1, l0, l1;
#pragma unroll
            for (int j = 0; j < 8; ++j) {
                h0.h[j] = us2h((ushort)(uu[j] & 0xffff));
                l0.h[j] = us2h((ushort)(uu[j] >> 16));
                h1.h[j] = us2h((ushort)(uu[8 + j] & 0xffff));
                l1.h[j] = us2h((ushort)(uu[8 + j] >> 16));
            }
            int bh = c16 * 2;
            *reinterpret_cast<uint4*>(sA + (r << 8) + ((bh +  0) ^ sw)) = h0.u;
            *reinterpret_cast<uint4*>(sA + (r << 8) + ((bh + 16) ^ sw)) = h1.u;
            *reinterpret_cast<uint4*>(sA + (r << 8) + (128 + ((bh +  0) ^ sw))) = l0.u;
            *reinterpret_cast<uint4*>(sA + (r << 8) + (128 + ((bh + 16) ^ sw))) = l1.u;
        }
        // W
#pragma unroll
        for (int i = 0; i < 5; ++i) {
            int cid = t + i * 256;
            int row = cid >> 4;
            int sl = cid & 15;
            int sw = (row & 7) << 4;
            int byte = (sl >> 3) * 128 + (((sl & 7) * 16) ^ sw);
            *reinterpret_cast<uint4*>(sW + (row << 8) + byte) = pw[i];
        }
        __syncthreads();
        if (kt < 11) { loadA((kt + 1) * 64); loadW((kt + 1) * 64); }
#pragma unroll
        for (int ks = 0; ks < 2; ++ks) {
            int hb = ks * 64 + hi2 * 16;
            int rA = w * 16 + lr;
            int swA = (rA & 7) << 4;
            f16x8 ah = *reinterpret_cast<const f16x8*>(sA + (rA << 8) + (hb ^ swA));
            f16x8 al = *reinterpret_cast<const f16x8*>(sA + (rA << 8) + (128 + (hb ^ swA)));
#pragma unroll
            for (int nf = 0; nf < 5; ++nf) {
                int rB = nf * 16 + lr;
                int swB = (rB & 7) << 4;
                f16x8 bh = *reinterpret_cast<const f16x8*>(sW + (rB << 8) + (hb ^ swB));
                f16x8 bl = *reinterpret_cast<const f16x8*>(sW + (rB << 8) + (128 + (hb ^ swB)));
                acc[nf] = __builtin_amdgcn_mfma_f32_16x16x32_f16(ah, bh, acc[nf], 0, 0, 0);
                acc[nf] = __builtin_amdgcn_mfma_f32_16x16x32_f16(al, bh, acc[nf], 0, 0, 0);
                acc[nf] = __builtin_amdgcn_mfma_f32_16x16x32_f16(ah, bl, acc[nf], 0, 0, 0);
            }
        }
    }

    // epilogue: unscale (256*1024), bias, logits + first-index argmax
    const float inv = 1.0f / 262144.f;
#pragma unroll
    for (int j = 0; j < 4; ++j) {
        int row = s0 + w * 16 + hi2 * 4 + j;
        float bestv = -1e38f;
        int besti = 0;
#pragma unroll
        for (int nf = 0; nf < 5; ++nf) {
            int col = nf * 16 + lr;
            float v = -1e38f;
            if (col < TT) {
                v = acc[nf][j] * inv + bt[col];
                logits[(size_t)row * TT + col] = v;
            }
            if (v > bestv) { bestv = v; besti = col; }
        }
#pragma unroll
        for (int off = 8; off > 0; off >>= 1) {
            float ov = __shfl_xor(bestv, off, 16);
            int oi = __shfl_xor(besti, off, 16);
            if (ov > bestv || (ov == bestv && oi < besti)) { bestv = ov; besti = oi; }
        }
        if (lr == 0) hat[row] = (float)besti;
    }
}

// ---------------- K3a: span-mean pooling. grid (24, 64). (proven verbatim)
__global__ __launch_bounds__(256) void pool_kernel(
    const uint* __restrict__ xfc, const int* __restrict__ head_idx,
    const int* __restrict__ cand_spans, const int* __restrict__ trig_spans,
    float* __restrict__ pooled)
{
    const int n = blockIdx.x;   // 0..23 (0-7 trig, 8-23 cand)
    const int b = blockIdx.y;
    __shared__ int sh_rows[8];
    __shared__ int sh_len;
    __shared__ int sh_st;
    __shared__ float sh_inv;
    const int t = threadIdx.x;
    if (t == 0) {
        const int* sp = (n < 8) ? (trig_spans + (b * 8 + n) * 2)
                                : (cand_spans + (b * 16 + (n - 8)) * 2);
        int st = sp[0], en = sp[1];
        int len = en - st;
        if (len < 0) len = 0;
        if (len > 8) len = 8;
        sh_len = len;
        sh_st = st;
        sh_inv = (1.f / (float)(len > 0 ? len : 1)) * (1.f / 256.f);
    }
    __syncthreads();
    if (t < sh_len) sh_rows[t] = (b << 9) + head_idx[(b << 9) + sh_st + t];
    __syncthreads();
    const int len = sh_len;
    const float inv = sh_inv;
#pragma unroll
    for (int j = 0; j < 3; ++j) {
        int c = t + j * 256;
        float s = 0.f;
        for (int p = 0; p < len; ++p) {
            uint u = xfc[(size_t)sh_rows[p] * DB + c];
            s += (float)us2h((ushort)(u & 0xffff)) + (float)us2h((ushort)(u >> 16));
        }
        pooled[((size_t)b * 24 + n) * DB + c] = s * inv;
    }
}

// ---------------- K3b: argument_hidden broadcast write [64][8][16][1536]
__global__ __launch_bounds__(256) void arg_kernel(
    const float* __restrict__ pooled, float* __restrict__ out2)
{
    int g = blockIdx.x * 256 + threadIdx.x;
    int b = g / 49152;
    int rem = g - b * 49152;
    int pair = rem / 384;
    int off4 = rem - pair * 384;
    int ti = pair >> 4;
    int c = pair & 15;
    int col = off4 << 2;
    const float* src;
    if (col < DB) src = pooled + ((size_t)(b * 24 + ti)) * DB + col;
    else          src = pooled + ((size_t)(b * 24 + 8 + c)) * DB + (col - DB);
    float4 v = *reinterpret_cast<const float4*>(src);
    *reinterpret_cast<float4*>(out2 + ((size_t)g << 2)) = v;
}

extern "C" void kernel_launch(void* const* d_in, const int* in_sizes, int n_in,
                              void* d_out, int out_size, void* d_ws, size_t ws_size,
                              hipStream_t stream)
{
    const float* enc   = (const float*)d_in[0];
    const float* table = (const float*)d_in[1];
    const float* fc1w  = (const float*)d_in[2];
    const float* fc1b  = (const float*)d_in[3];
    const float* trigw = (const float*)d_in[4];
    const float* trigb = (const float*)d_in[5];
    const int*   ex    = (const int*)d_in[6];
    const int*   hidx  = (const int*)d_in[7];
    const int*   cspan = (const int*)d_in[8];
    const int*   tspan = (const int*)d_in[9];

    float* out0 = (float*)d_out;
    float* out1 = out0 + (size_t)BS_TOTAL * TT;
    float* out2 = out1 + BS_TOTAL;

    uint*  ws_xfc  = (uint*)d_ws;                                    // [32768][768] packed f16 h/l
    float* ws_pool = (float*)(ws_xfc + (size_t)BS_TOTAL * DB);       // [64][24][768]
    _Float16* wsWf  = (_Float16*)(ws_pool + (size_t)64 * 24 * DB);   // frag-linear [2496*512]
    _Float16* wsT0  = wsWf + (size_t)2496 * 512;                     // [80][768]
    _Float16* wsT1  = wsT0 + (size_t)80 * DB;
    _Float16* wsAhi = wsT1 + (size_t)80 * DB;                        // [32768][832]
    _Float16* wsAlo = wsAhi + (size_t)BS_TOTAL * KV;                 // [32768][832]

    presplit_kernel<<<dim3(BS_TOTAL * 104 / 256), dim3(256), 0, stream>>>(enc, ex, table, wsAhi, wsAlo);
    packwf_kernel<<<dim3(1248), dim3(64), 0, stream>>>(fc1w, wsWf);
    splitw_trig<<<dim3(80), dim3(256), 0, stream>>>(trigw, wsT0, wsT1);
    fc1_mfma<<<dim3(1536), dim3(256), 0, stream>>>(wsAhi, wsAlo, wsWf, fc1b, ws_xfc);
    trig_mfma<<<dim3(BS_TOTAL / 64), dim3(256), 0, stream>>>(
        ws_xfc, hidx, wsT0, wsT1, trigb, out0, out1);
    pool_kernel<<<dim3(24, 64), dim3(256), 0, stream>>>(ws_xfc, hidx, cspan, tspan, ws_pool);
    arg_kernel<<<dim3(3145728 / 256), dim3(256), 0, stream>>>(ws_pool, out2);
}

// Round 18
// 247.326 us; speedup vs baseline: 1.5845x; 1.5845x over previous
//
#include <hip/hip_runtime.h>

#define BS_TOTAL 32768   // B*S
#define DB 768
#define KV 832           // padded K: 768 enc + 50 ent + 14 zero
#define KREAL 818
#define TT 68
#define SEQ 512

typedef float v2f __attribute__((ext_vector_type(2)));
typedef float f32x4 __attribute__((ext_vector_type(4)));
typedef _Float16 f16x8 __attribute__((ext_vector_type(8)));
typedef _Float16 f16x4 __attribute__((ext_vector_type(4)));
typedef unsigned int uint;
typedef unsigned short ushort;

union U4 { uint4 u; f16x8 h; };

__device__ __forceinline__ _Float16 us2h(ushort x){ union{ushort u;_Float16 h;}c; c.u=x; return c.h; }
__device__ __forceinline__ ushort h2us(_Float16 x){ union{ushort u;_Float16 h;}c; c.h=x; return c.u; }
__device__ __forceinline__ uint packx(float xs){
    _Float16 h=(_Float16)xs; _Float16 l=(_Float16)(xs-(float)h);
    return (uint)h2us(h) | ((uint)h2us(l)<<16);
}

// ---------------- K0a: pack fc1 W into MFMA-fragment-linear f16 hi/lo slabs (x1024).
// (R16-proven verbatim)
__global__ __launch_bounds__(64) void packwf_kernel(
    const float* __restrict__ W, _Float16* __restrict__ Wf)
{
    const int bid = blockIdx.x;          // 6*13*16 = 1248
    const int l = threadIdx.x;
    const int bn = bid / 208;
    const int rem = bid % 208;
    const int kt = rem >> 4;
    const int sub = rem & 15;
    const int ks = sub >> 3;
    const int nfg = sub & 7;
    const int row = bn * 128 + nfg * 16 + (l & 15);
    const int kb = kt * 64 + ks * 32 + ((l >> 4) << 3);
    f16x8 hi, lo;
#pragma unroll
    for (int q = 0; q < 8; ++q) {
        int k = kb + q;
        float v = (k < KREAL) ? W[(size_t)row * KREAL + k] * 1024.f : 0.f;
        _Float16 h = (_Float16)v;
        hi[q] = h; lo[q] = (_Float16)(v - (float)h);
    }
    const size_t fb = ((((size_t)bn * 13 + kt) * 2 + ks) * 8 + nfg) * 2;
    *reinterpret_cast<f16x8*>(Wf + (fb + 0) * 512 + l * 8) = hi;
    *reinterpret_cast<f16x8*>(Wf + (fb + 1) * 512 + l * 8) = lo;
}

// ---------------- K0b: split trig W rows -> T0/T1 row-major [80][768], x1024 (proven verbatim)
__global__ __launch_bounds__(256) void splitw_trig(
    const float* __restrict__ Wt, _Float16* __restrict__ T0, _Float16* __restrict__ T1)
{
    int r2 = blockIdx.x;               // 0..79
    int t = threadIdx.x;
#pragma unroll
    for (int j = 0; j < 3; ++j) {
        int k = t * 3 + j;
        if (k < DB) {
            float v = (r2 < TT) ? Wt[(size_t)r2 * DB + k] * 1024.f : 0.f;
            _Float16 h = (_Float16)v;
            T0[(size_t)r2 * DB + k] = h;
            T1[(size_t)r2 * DB + k] = (_Float16)(v - (float)h);
        }
    }
}

// ---------------- K1: fc1 via fp32-emu fp16 MFMA. R16-proven body with ONE change:
// double-buffered A-LDS (64 KB, bufA/bufB), ONE barrier per K-tile instead of two —
// ds_writes of tile kt+1 overlap MFMA of tile kt (different 32 KB regions).
// A-split staging math, W-fragment register path, epilogue: byte-identical to R16.
__global__ __launch_bounds__(256, 2) void fc1_mfma(
    const float* __restrict__ enc, const int* __restrict__ ex,
    const float* __restrict__ table, const _Float16* __restrict__ Wf,
    const float* __restrict__ bias, uint* __restrict__ xout)
{
    __shared__ char lds[65536];   // bufA: sA0@0,sA1@16K ; bufB: sA0@32K,sA1@48K
    const int t = threadIdx.x;
    const int l = t & 63;
    const int w = t >> 6;
    const int wr = w >> 1, wc = w & 1;
    const int lr = l & 15, hi2 = l >> 4;
    const int bm0 = blockIdx.x * 128;
    const int by = blockIdx.y;
    const int bn0 = by * 128;

    f32x4 acc[4][4];
#pragma unroll
    for (int i = 0; i < 4; ++i)
#pragma unroll
        for (int j = 0; j < 4; ++j) acc[i][j] = (f32x4){0.f, 0.f, 0.f, 0.f};

    float4 pa[8];     // A prefetch (fp32, 128x64 per tile)
    uint4 bf[8];      // B fragments for one ks

    auto loadA = [&](int k0) {
        if (k0 < DB) {
#pragma unroll
            for (int c = 0; c < 8; ++c) {
                int idx = t + c * 256;
                int r = idx >> 4;
                int c4 = (idx & 15) << 2;
                pa[c] = *reinterpret_cast<const float4*>(enc + (size_t)(bm0 + r) * DB + k0 + c4);
            }
        } else {  // last tile: cols 768..831 = ent gather (e<50) else 0
#pragma unroll
            for (int c = 0; c < 8; ++c) {
                int idx = t + c * 256;
                int r = idx >> 4;
                int c4 = (idx & 15) << 2;
                const int* exr = ex + (size_t)(bm0 + r) * 3;
                int i0 = exr[0] * 50, i1 = exr[1] * 50, i2 = exr[2] * 50;
                float vv[4];
#pragma unroll
                for (int j = 0; j < 4; ++j) {
                    int e = c4 + j;
                    vv[j] = (e < 50) ? (table[i0 + e] + table[i1 + e] + table[i2 + e]) : 0.f;
                }
                pa[c] = make_float4(vv[0], vv[1], vv[2], vv[3]);
            }
        }
    };
    // stage pa -> (dst0, dst1): R16-proven split + swizzled ds_writes, parametrized dest
    auto stageA = [&](char* dst0, char* dst1) {
#pragma unroll
        for (int c = 0; c < 8; ++c) {
            int idx = t + c * 256;
            int r = idx >> 4;
            int b0 = (idx & 15) << 3;              // byte offset in 128B row
            int off = (r << 7) + (b0 ^ ((r & 7) << 4));
            float f0 = pa[c].x * 32.f, f1 = pa[c].y * 32.f;
            float f2 = pa[c].z * 32.f, f3 = pa[c].w * 32.f;
            _Float16 h0 = (_Float16)f0, h1 = (_Float16)f1, h2 = (_Float16)f2, h3 = (_Float16)f3;
            f16x4 hi = {h0, h1, h2, h3};
            f16x4 lo = {(_Float16)(f0 - (float)h0), (_Float16)(f1 - (float)h1),
                        (_Float16)(f2 - (float)h2), (_Float16)(f3 - (float)h3)};
            *reinterpret_cast<f16x4*>(dst0 + off) = hi;
            *reinterpret_cast<f16x4*>(dst1 + off) = lo;
        }
    };
    auto loadBf = [&](int kt, int ks) {
        const size_t fb = ((((size_t)by * 13 + kt) * 2 + ks) * 8 + wc * 4) * 2;
        const _Float16* base = Wf + fb * 512 + l * 8;
#pragma unroll
        for (int q = 0; q < 8; ++q)
            bf[q] = *reinterpret_cast<const uint4*>(base + (size_t)q * 512);
    };

    // prologue: tile 0 staged to bufA; tile 1 prefetched to regs
    loadA(0); loadBf(0, 0);
    stageA(lds, lds + 16384);
    loadA(64);
    __syncthreads();

    for (int kt = 0; kt < 13; ++kt) {
        char* cs0 = lds + (kt & 1) * 32768;          // compute buffer
        char* cs1 = cs0 + 16384;
        char* ws0 = lds + ((kt + 1) & 1) * 32768;    // write buffer (other 32 KB)
        char* ws1 = ws0 + 16384;
        if (kt < 12) stageA(ws0, ws1);               // overlap ds_write with MFMA below
        if (kt < 11) loadA((kt + 2) * 64);           // prefetch tile kt+2
        // ---- compute: 2 k-steps; B frags from registers, A frags from LDS (R16-proven)
#pragma unroll
        for (int ks = 0; ks < 2; ++ks) {
            const int kb = ks * 64 + (hi2 << 4);
            f16x8 a0f[4], a1f[4], b0f[4], b1f[4];
#pragma unroll
            for (int mf = 0; mf < 4; ++mf) {
                int r = wr * 64 + mf * 16 + lr;
                int off = (r << 7) + (kb ^ ((r & 7) << 4));
                a0f[mf] = *reinterpret_cast<const f16x8*>(cs0 + off);
                a1f[mf] = *reinterpret_cast<const f16x8*>(cs1 + off);
            }
#pragma unroll
            for (int nf = 0; nf < 4; ++nf) {
                U4 u0, u1;
                u0.u = bf[nf * 2 + 0];
                u1.u = bf[nf * 2 + 1];
                b0f[nf] = u0.h;
                b1f[nf] = u1.h;
            }
            if (ks == 0) loadBf(kt, 1);
            else if (kt < 12) loadBf(kt + 1, 0);
#pragma unroll
            for (int mf = 0; mf < 4; ++mf)
#pragma unroll
                for (int nf = 0; nf < 4; ++nf) {
                    acc[mf][nf] = __builtin_amdgcn_mfma_f32_16x16x32_f16(a0f[mf], b0f[nf], acc[mf][nf], 0, 0, 0);
                    acc[mf][nf] = __builtin_amdgcn_mfma_f32_16x16x32_f16(a1f[mf], b0f[nf], acc[mf][nf], 0, 0, 0);
                    acc[mf][nf] = __builtin_amdgcn_mfma_f32_16x16x32_f16(a0f[mf], b1f[nf], acc[mf][nf], 0, 0, 0);
                }
        }
        __syncthreads();   // next-iter compute may read ws; next-iter ds_write hits cs
    }

    // ---- epilogue (R16-proven): unscale 2^-15, bias, relu, pack(x*256), LDS-staged stores
    const float inv0 = 1.0f / 32768.f;
    uint* sE = reinterpret_cast<uint*>(lds);   // [32][132]
    float bv[4];
#pragma unroll
    for (int nf = 0; nf < 4; ++nf) bv[nf] = bias[bn0 + wc * 64 + nf * 16 + lr];

#pragma unroll
    for (int p = 0; p < 4; ++p) {
        __syncthreads();
        if (wr == (p >> 1)) {
#pragma unroll
            for (int mi = 0; mi < 2; ++mi) {
                int mf = (p & 1) * 2 + mi;
                int rowl = mf * 16 + hi2 * 4 - (p & 1) * 32;
#pragma unroll
                for (int nf = 0; nf < 4; ++nf) {
                    int col = wc * 64 + nf * 16 + lr;
#pragma unroll
                    for (int j = 0; j < 4; ++j) {
                        float x = fmaxf(acc[mf][nf][j] * inv0 + bv[nf], 0.f);
                        sE[(rowl + j) * 132 + col] = packx(x * 256.f);
                    }
                }
            }
        }
        __syncthreads();
        int rrow = t >> 3;
        int c0 = (t & 7) << 4;
        uint* gp = xout + (size_t)(bm0 + p * 32 + rrow) * DB + bn0 + c0;
        const uint* sp = sE + rrow * 132 + c0;
#pragma unroll
        for (int q = 0; q < 4; ++q)
            *reinterpret_cast<uint4*>(gp + q * 4) = *reinterpret_cast<const uint4*>(sp + q * 4);
    }
}

// ---------------- K2: trig GEMM via emu-MFMA. 64 gathered rows/block, N=80 (5 nf), BK=64.
// (R8/R15/R16-proven verbatim)
__global__ __launch_bounds__(256, 4) void trig_mfma(
    const uint* __restrict__ xfc, const int* __restrict__ head_idx,
    const _Float16* __restrict__ T0, const _Float16* __restrict__ T1,
    const float* __restrict__ bt, float* __restrict__ logits, float* __restrict__ hat)
{
    __shared__ char sA[16384];   // [64][256B]: hi 0-127 | lo 128-255
    __shared__ char sW[20480];   // [80][256B]
    __shared__ int srow[64];
    const int t = threadIdx.x;
    const int l = t & 63;
    const int w = t >> 6;
    const int lr = l & 15, hi2 = l >> 4;
    const int s0 = blockIdx.x * 64;
    if (t < 64) srow[t] = (((s0 + t) >> 9) << 9) + head_idx[s0 + t];
    __syncthreads();

    f32x4 acc[5];
#pragma unroll
    for (int n = 0; n < 5; ++n) acc[n] = (f32x4){0.f, 0.f, 0.f, 0.f};

    uint4 pa[4];
    uint4 pw[5];

    auto loadA = [&](int k0) {
        int r = t >> 2, c16 = (t & 3) << 4;
        const uint* src = xfc + (size_t)srow[r] * DB + k0 + c16;
#pragma unroll
        for (int q = 0; q < 4; ++q) pa[q] = *reinterpret_cast<const uint4*>(src + q * 4);
    };
    auto loadW = [&](int k0) {
#pragma unroll
        for (int i = 0; i < 5; ++i) {
            int cid = t + i * 256;
            int row = cid >> 4;
            int sl = cid & 15;
            const _Float16* src = ((sl >> 3) ? T1 : T0) + (size_t)row * DB + k0 + (sl & 7) * 8;
            pw[i] = *reinterpret_cast<const uint4*>(src);
        }
    };

    loadA(0); loadW(0);

    for (int kt = 0; kt < 12; ++kt) {
        __syncthreads();
        // A: unpack 16 packed uints -> hi/lo f16 planes
        {
            int r = t >> 2, c16 = (t & 3) << 4;
            int sw = (r & 7) << 4;
            uint uu[16];
#pragma unroll
            for (int q = 0; q < 4; ++q) *reinterpret_cast<uint4*>(uu + q * 4) = pa[q];
            U4 h0, h1, l0, l1;
#pragma unroll
            for (int j = 0; j < 8; ++j) {
                h0.h[j] = us2h((ushort)(uu[j] & 0xffff));
                l0.h[j] = us2h((ushort)(uu[j] >> 16));
                h1.h[j] = us2h((ushort)(uu[8 + j] & 0xffff));
                l1.h[j] = us2h((ushort)(uu[8 + j] >> 16));
            }
            int bh = c16 * 2;
            *reinterpret_cast<uint4*>(sA + (r << 8) + ((bh +  0) ^ sw)) = h0.u;
            *reinterpret_cast<uint4*>(sA + (r << 8) + ((bh + 16) ^ sw)) = h1.u;
            *reinterpret_cast<uint4*>(sA + (r << 8) + (128 + ((bh +  0) ^ sw))) = l0.u;
            *reinterpret_cast<uint4*>(sA + (r << 8) + (128 + ((bh + 16) ^ sw))) = l1.u;
        }
        // W
#pragma unroll
        for (int i = 0; i < 5; ++i) {
            int cid = t + i * 256;
            int row = cid >> 4;
            int sl = cid & 15;
            int sw = (row & 7) << 4;
            int byte = (sl >> 3) * 128 + (((sl & 7) * 16) ^ sw);
            *reinterpret_cast<uint4*>(sW + (row << 8) + byte) = pw[i];
        }
        __syncthreads();
        if (kt < 11) { loadA((kt + 1) * 64); loadW((kt + 1) * 64); }
#pragma unroll
        for (int ks = 0; ks < 2; ++ks) {
            int hb = ks * 64 + hi2 * 16;
            int rA = w * 16 + lr;
            int swA = (rA & 7) << 4;
            f16x8 ah = *reinterpret_cast<const f16x8*>(sA + (rA << 8) + (hb ^ swA));
            f16x8 al = *reinterpret_cast<const f16x8*>(sA + (rA << 8) + (128 + (hb ^ swA)));
#pragma unroll
            for (int nf = 0; nf < 5; ++nf) {
                int rB = nf * 16 + lr;
                int swB = (rB & 7) << 4;
                f16x8 bh = *reinterpret_cast<const f16x8*>(sW + (rB << 8) + (hb ^ swB));
                f16x8 bl = *reinterpret_cast<const f16x8*>(sW + (rB << 8) + (128 + (hb ^ swB)));
                acc[nf] = __builtin_amdgcn_mfma_f32_16x16x32_f16(ah, bh, acc[nf], 0, 0, 0);
                acc[nf] = __builtin_amdgcn_mfma_f32_16x16x32_f16(al, bh, acc[nf], 0, 0, 0);
                acc[nf] = __builtin_amdgcn_mfma_f32_16x16x32_f16(ah, bl, acc[nf], 0, 0, 0);
            }
        }
    }

    // epilogue: unscale (256*1024), bias, logits + first-index argmax
    const float inv = 1.0f / 262144.f;
#pragma unroll
    for (int j = 0; j < 4; ++j) {
        int row = s0 + w * 16 + hi2 * 4 + j;
        float bestv = -1e38f;
        int besti = 0;
#pragma unroll
        for (int nf = 0; nf < 5; ++nf) {
            int col = nf * 16 + lr;
            float v = -1e38f;
            if (col < TT) {
                v = acc[nf][j] * inv + bt[col];
                logits[(size_t)row * TT + col] = v;
            }
            if (v > bestv) { bestv = v; besti = col; }
        }
#pragma unroll
        for (int off = 8; off > 0; off >>= 1) {
            float ov = __shfl_xor(bestv, off, 16);
            int oi = __shfl_xor(besti, off, 16);
            if (ov > bestv || (ov == bestv && oi < besti)) { bestv = ov; besti = oi; }
        }
        if (lr == 0) hat[row] = (float)besti;
    }
}

// ---------------- K3a: span-mean pooling. grid (24, 64). (proven verbatim)
__global__ __launch_bounds__(256) void pool_kernel(
    const uint* __restrict__ xfc, const int* __restrict__ head_idx,
    const int* __restrict__ cand_spans, const int* __restrict__ trig_spans,
    float* __restrict__ pooled)
{
    const int n = blockIdx.x;   // 0..23 (0-7 trig, 8-23 cand)
    const int b = blockIdx.y;
    __shared__ int sh_rows[8];
    __shared__ int sh_len;
    __shared__ int sh_st;
    __shared__ float sh_inv;
    const int t = threadIdx.x;
    if (t == 0) {
        const int* sp = (n < 8) ? (trig_spans + (b * 8 + n) * 2)
                                : (cand_spans + (b * 16 + (n - 8)) * 2);
        int st = sp[0], en = sp[1];
        int len = en - st;
        if (len < 0) len = 0;
        if (len > 8) len = 8;
        sh_len = len;
        sh_st = st;
        sh_inv = (1.f / (float)(len > 0 ? len : 1)) * (1.f / 256.f);
    }
    __syncthreads();
    if (t < sh_len) sh_rows[t] = (b << 9) + head_idx[(b << 9) + sh_st + t];
    __syncthreads();
    const int len = sh_len;
    const float inv = sh_inv;
#pragma unroll
    for (int j = 0; j < 3; ++j) {
        int c = t + j * 256;
        float s = 0.f;
        for (int p = 0; p < len; ++p) {
            uint u = xfc[(size_t)sh_rows[p] * DB + c];
            s += (float)us2h((ushort)(u & 0xffff)) + (float)us2h((ushort)(u >> 16));
        }
        pooled[((size_t)b * 24 + n) * DB + c] = s * inv;
    }
}

// ---------------- K3b: argument_hidden broadcast write [64][8][16][1536]
__global__ __launch_bounds__(256) void arg_kernel(
    const float* __restrict__ pooled, float* __restrict__ out2)
{
    int g = blockIdx.x * 256 + threadIdx.x;
    int b = g / 49152;
    int rem = g - b * 49152;
    int pair = rem / 384;
    int off4 = rem - pair * 384;
    int ti = pair >> 4;
    int c = pair & 15;
    int col = off4 << 2;
    const float* src;
    if (col < DB) src = pooled + ((size_t)(b * 24 + ti)) * DB + col;
    else          src = pooled + ((size_t)(b * 24 + 8 + c)) * DB + (col - DB);
    float4 v = *reinterpret_cast<const float4*>(src);
    *reinterpret_cast<float4*>(out2 + ((size_t)g << 2)) = v;
}

extern "C" void kernel_launch(void* const* d_in, const int* in_sizes, int n_in,
                              void* d_out, int out_size, void* d_ws, size_t ws_size,
                              hipStream_t stream)
{
    const float* enc   = (const float*)d_in[0];
    const float* table = (const float*)d_in[1];
    const float* fc1w  = (const float*)d_in[2];
    const float* fc1b  = (const float*)d_in[3];
    const float* trigw = (const float*)d_in[4];
    const float* trigb = (const float*)d_in[5];
    const int*   ex    = (const int*)d_in[6];
    const int*   hidx  = (const int*)d_in[7];
    const int*   cspan = (const int*)d_in[8];
    const int*   tspan = (const int*)d_in[9];

    float* out0 = (float*)d_out;
    float* out1 = out0 + (size_t)BS_TOTAL * TT;
    float* out2 = out1 + BS_TOTAL;

    uint*  ws_xfc  = (uint*)d_ws;                                    // [32768][768] packed f16 h/l
    float* ws_pool = (float*)(ws_xfc + (size_t)BS_TOTAL * DB);       // [64][24][768]
    _Float16* wsWf = (_Float16*)(ws_pool + (size_t)64 * 24 * DB);    // frag-linear [2496*512]
    _Float16* wsT0 = wsWf + (size_t)2496 * 512;                      // [80][768]
    _Float16* wsT1 = wsT0 + (size_t)80 * DB;

    packwf_kernel<<<dim3(1248), dim3(64), 0, stream>>>(fc1w, wsWf);
    splitw_trig<<<dim3(80), dim3(256), 0, stream>>>(trigw, wsT0, wsT1);
    fc1_mfma<<<dim3(BS_TOTAL / 128, DB / 128), dim3(256), 0, stream>>>(
        enc, ex, table, wsWf, fc1b, ws_xfc);
    trig_mfma<<<dim3(BS_TOTAL / 64), dim3(256), 0, stream>>>(
        ws_xfc, hidx, wsT0, wsT1, trigb, out0, out1);
    pool_kernel<<<dim3(24, 64), dim3(256), 0, stream>>>(ws_xfc, hidx, cspan, tspan, ws_pool);
    arg_kernel<<<dim3(3145728 / 256), dim3(256), 0, stream>>>(ws_pool, out2);
}